// Round 14
// baseline (113.889 us; speedup 1.0000x reference)
//
#include <hip/hip_runtime.h>
#include <hip/hip_bf16.h>

#define TT 512
#define RS 16       // activation row: 16 f16 ch-slots (32 B)
#define RH 8        // row halo (t=-8..519 -> rows 0..527)
#define NROW 528
#define K_FC 5120

typedef _Float16 h8 __attribute__((ext_vector_type(8)));
typedef float f32x16 __attribute__((ext_vector_type(16)));
typedef __attribute__((address_space(1))) const void GAS;
typedef __attribute__((address_space(3))) void LAS;

__device__ __forceinline__ float fast_tanh(float v) {
    float e = __expf(2.0f * v);
    return 1.0f - 2.0f / (e + 1.0f);
}
__device__ __forceinline__ unsigned pk(float a, float b) {
    return __builtin_bit_cast(unsigned, __builtin_amdgcn_cvt_pkrtz(a, b));
}

// ---------------------------------------------------------------------------
// wtab in MFMA A-fragment layout (32x32x16 f16): lane l -> row=l&31, k=(l>>5)*8+e
//  conv2 @0 (5j) | conv3 @320 (7j) | d1 @768 (5j) | d2 @1088 (5j)
//  cross @1408 (A[kc][ch]=2*code[ch][kc]) | q @1472 (2 ks)
//  c2tab: 32 f32 bits of (4 - sum_c code[c][k]^2)
// Also zeros the 64 per-tile fc counters (replay determinism).
__global__ __launch_bounds__(256) void prep_wtab_kernel(
    const float* __restrict__ w2, const float* __restrict__ w3,
    const float* __restrict__ d1w, const float* __restrict__ d2w,
    const float* __restrict__ code, uint4* __restrict__ wtab,
    unsigned* __restrict__ c2tab, unsigned* __restrict__ tilecnt)
{
    const int i = blockIdx.x * 256 + threadIdx.x;
    if (i < 1600) {
        const int lane = i & 63;
        const int o = lane & 31;
        const int hi = lane >> 5;
        h8 v = {};
        if (i < 320) {
            const int j = i >> 6;
            #pragma unroll
            for (int e = 0; e < 8; ++e) {
                int k = hi * 8 + e;
                if (o < 10 && k < 5) v[e] = (_Float16)w2[(o * 5 + k) * 5 + j];
            }
        } else if (i < 768) {
            const int j = (i - 320) >> 6;
            #pragma unroll
            for (int e = 0; e < 8; ++e) {
                int k = hi * 8 + e;
                if (o < 10 && k < 10) v[e] = (_Float16)w3[(o * 10 + k) * 7 + j];
            }
        } else if (i < 1088) {
            const int j = (i - 768) >> 6;
            #pragma unroll
            for (int e = 0; e < 8; ++e) {
                int k = hi * 8 + e;
                if (o < 10 && k < 10) v[e] = (_Float16)d1w[(o * 10 + k) * 5 + j];
            }
        } else if (i < 1408) {
            const int j = (i - 1088) >> 6;
            #pragma unroll
            for (int e = 0; e < 8; ++e) {
                int k = hi * 8 + e;
                if (o < 10 && k < 10) v[e] = (_Float16)d2w[(o * 10 + k) * 5 + j];
            }
        } else if (i < 1472) {
            #pragma unroll
            for (int e = 0; e < 8; ++e) {
                int ch = hi * 8 + e;
                if (ch < 10) v[e] = (_Float16)(2.0f * code[ch * 32 + o]);
            }
        } else {
            const int ks = (i - 1472) >> 6;
            #pragma unroll
            for (int e = 0; e < 8; ++e) {
                int kc = ks * 16 + hi * 8 + e;
                if (o < 10) v[e] = (_Float16)code[o * 32 + kc];
            }
        }
        wtab[i] = __builtin_bit_cast(uint4, v);
    } else if (i < 1632) {
        int k = i - 1600;
        float s = 0.f;
        for (int c = 0; c < 10; ++c) { float cv = code[c * 32 + k]; s = fmaf(cv, cv, s); }
        c2tab[k] = __float_as_uint(4.0f - s);
    } else if (i < 1696) {
        tilecnt[i - 1632] = 0u;
    }
}

// ---------------------------------------------------------------------------
// Conv stage via J MFMAs per 32-t tile; C-layout row m=(r&3)+8*(r>>2)+4*hi.
template<int J, int P, int ACT>   // ACT: 0 relu, 1 tanh
__device__ __forceinline__ void conv_stage(
    const _Float16* __restrict__ src, _Float16* __restrict__ dst,
    const uint4* __restrict__ wtab, int wbase, const float* __restrict__ bsrc)
{
    const int tid = threadIdx.x;
    const int lane = tid & 63;
    const int wv = tid >> 6;
    const int l31 = lane & 31;
    const int hi = lane >> 5;

    uint4 wf[J];
    #pragma unroll
    for (int j = 0; j < J; ++j) wf[j] = wtab[wbase + j * 64 + lane];
    float bias[6];
    #pragma unroll
    for (int r = 0; r < 6; ++r) {
        int m = (r & 3) + 8 * (r >> 2) + 4 * hi;
        bias[r] = (m < 10) ? bsrc[m] : 0.f;
    }

    #pragma unroll 2
    for (int tile = 0; tile < 4; ++tile) {
        const int tcol = wv * 128 + tile * 32 + l31;
        f32x16 acc = {};
        #pragma unroll
        for (int j = 0; j < J; ++j) {
            h8 bf = *(const h8*)(src + (tcol + RH - P + j) * RS + hi * 8);
            acc = __builtin_amdgcn_mfma_f32_32x32x16_f16(
                __builtin_bit_cast(h8, wf[j]), bf, acc, 0, 0, 0);
        }
        float v[6];
        #pragma unroll
        for (int r = 0; r < 6; ++r) {
            float t = acc[r] + bias[r];
            v[r] = (ACT == 0) ? fmaxf(t, 0.f) : fast_tanh(t);
        }
        unsigned* drow = (unsigned*)(dst + (tcol + RH) * RS);
        uint2 s1v; s1v.x = pk(v[0], v[1]); s1v.y = pk(v[2], v[3]);
        *(uint2*)(drow + hi * 2) = s1v;
        if (!hi) drow[4] = pk(v[4], v[5]);
    }
}

// Final stage: relu, store straight to flat[c*512 + t] in global.
template<int J, int P>
__device__ __forceinline__ void conv_stage_flat(
    const _Float16* __restrict__ src, _Float16* __restrict__ flatrow,
    const uint4* __restrict__ wtab, int wbase, const float* __restrict__ bsrc)
{
    const int tid = threadIdx.x;
    const int lane = tid & 63;
    const int wv = tid >> 6;
    const int l31 = lane & 31;
    const int hi = lane >> 5;

    uint4 wf[J];
    #pragma unroll
    for (int j = 0; j < J; ++j) wf[j] = wtab[wbase + j * 64 + lane];
    float bias[6];
    #pragma unroll
    for (int r = 0; r < 6; ++r) {
        int m = (r & 3) + 8 * (r >> 2) + 4 * hi;
        bias[r] = (m < 10) ? bsrc[m] : 0.f;
    }

    #pragma unroll 2
    for (int tile = 0; tile < 4; ++tile) {
        const int tcol = wv * 128 + tile * 32 + l31;
        f32x16 acc = {};
        #pragma unroll
        for (int j = 0; j < J; ++j) {
            h8 bf = *(const h8*)(src + (tcol + RH - P + j) * RS + hi * 8);
            acc = __builtin_amdgcn_mfma_f32_32x32x16_f16(
                __builtin_bit_cast(h8, wf[j]), bf, acc, 0, 0, 0);
        }
        #pragma unroll
        for (int r = 0; r < 4; ++r)
            flatrow[(r + 4 * hi) * TT + tcol] = (_Float16)fmaxf(acc[r] + bias[r], 0.f);
        if (!hi) {
            flatrow[8 * TT + tcol] = (_Float16)fmaxf(acc[4] + bias[4], 0.f);
            flatrow[9 * TT + tcol] = (_Float16)fmaxf(acc[5] + bias[5], 0.f);
        }
    }
}

// VQ: 1 MFMA scores, exp, denom shfl, packed-f16 half-wave exchange, 2 MFMA q.
__device__ __forceinline__ void vq_stage(
    const _Float16* __restrict__ src, _Float16* __restrict__ dst,
    const uint4* __restrict__ wtab, const unsigned* __restrict__ c2tab)
{
    const int tid = threadIdx.x;
    const int lane = tid & 63;
    const int wv = tid >> 6;
    const int l31 = lane & 31;
    const int hi = lane >> 5;

    const h8 wcr = __builtin_bit_cast(h8, wtab[1408 + lane]);
    const h8 wq0 = __builtin_bit_cast(h8, wtab[1472 + lane]);
    const h8 wq1 = __builtin_bit_cast(h8, wtab[1536 + lane]);
    float c2s[16];
    #pragma unroll
    for (int r = 0; r < 16; ++r)
        c2s[r] = __uint_as_float(c2tab[(r & 3) + 8 * (r >> 2) + 4 * hi]);

    #pragma unroll 2
    for (int tile = 0; tile < 4; ++tile) {
        const int tcol = wv * 128 + tile * 32 + l31;
        h8 bf = *(const h8*)(src + (tcol + RH) * RS + hi * 8);
        f32x16 sacc = {};
        sacc = __builtin_amdgcn_mfma_f32_32x32x16_f16(wcr, bf, sacc, 0, 0, 0);

        float e[16], sum = 0.f;
        #pragma unroll
        for (int r = 0; r < 16; ++r) { e[r] = __expf(sacc[r] + c2s[r]); sum += e[r]; }
        float inv = 1.0f / (sum + __shfl_xor(sum, 32));

        unsigned epk[8], sopk[8];
        #pragma unroll
        for (int q = 0; q < 8; ++q) epk[q] = pk(e[2 * q], e[2 * q + 1]);
        #pragma unroll
        for (int q = 0; q < 8; ++q) sopk[q] = (unsigned)__shfl_xor((int)epk[q], 32);

        uint4 b0u, b1u;
        b0u.x = hi ? sopk[2] : epk[0]; b0u.y = hi ? sopk[3] : epk[1];
        b0u.z = hi ? epk[2] : sopk[0]; b0u.w = hi ? epk[3] : sopk[1];
        b1u.x = hi ? sopk[6] : epk[4]; b1u.y = hi ? sopk[7] : epk[5];
        b1u.z = hi ? epk[6] : sopk[4]; b1u.w = hi ? epk[7] : sopk[5];

        f32x16 qacc = {};
        qacc = __builtin_amdgcn_mfma_f32_32x32x16_f16(wq0, __builtin_bit_cast(h8, b0u), qacc, 0, 0, 0);
        qacc = __builtin_amdgcn_mfma_f32_32x32x16_f16(wq1, __builtin_bit_cast(h8, b1u), qacc, 0, 0, 0);

        float v[6];
        #pragma unroll
        for (int r = 0; r < 6; ++r) v[r] = qacc[r] * inv;
        unsigned* drow = (unsigned*)(dst + (tcol + RH) * RS);
        uint2 s1v; s1v.x = pk(v[0], v[1]); s1v.y = pk(v[2], v[3]);
        *(uint2*)(drow + hi * 2) = s1v;
        if (!hi) drow[4] = pk(v[4], v[5]);
    }
}

// ---------------------------------------------------------------------------
// Block-cooperative enc/dec (R11/R13 structure). Blocks >= nenc convert fcw
// f32->f16 (consumed only by the later fc launch).
__global__ __launch_bounds__(256, 4) void enc_dec_kernel(
    const float* __restrict__ x,
    const float* __restrict__ w1, const float* __restrict__ b1,
    const float* __restrict__ b2, const float* __restrict__ b3,
    const float* __restrict__ d1b, const float* __restrict__ d2b,
    const uint4* __restrict__ wtab, const unsigned* __restrict__ c2tab,
    _Float16* __restrict__ flat,
    const float* __restrict__ fcw, _Float16* __restrict__ fcw_h, int nenc)
{
    __shared__ __align__(16) _Float16 bufA[NROW * RS];
    __shared__ __align__(16) _Float16 bufB[NROW * RS];

    const int tid = threadIdx.x;
    const int bid = blockIdx.x;

    if (bid >= nenc) {   // fcw f32 -> f16 conversion
        int i = (bid - nenc) * 256 + tid;
        float4 a = ((const float4*)fcw)[i * 2];
        float4 b4 = ((const float4*)fcw)[i * 2 + 1];
        h8 v;
        v[0] = (_Float16)a.x;  v[1] = (_Float16)a.y;
        v[2] = (_Float16)a.z;  v[3] = (_Float16)a.w;
        v[4] = (_Float16)b4.x; v[5] = (_Float16)b4.y;
        v[6] = (_Float16)b4.z; v[7] = (_Float16)b4.w;
        *(h8*)&fcw_h[(size_t)i * 8] = v;
        return;
    }

    // ---- init: zero bufA halo rows (conv1 writes the rest) + all of bufB ----
    if (tid < 32) {
        int r = tid >> 1, half = tid & 1;
        int rowz = (r < 8) ? r : 512 + r;       // rows 0..7, 520..527
        uint4 z = {0, 0, 0, 0};
        *(uint4*)(bufA + rowz * RS + half * 8) = z;
    }
    {
        uint4 z = {0, 0, 0, 0};
        uint4* pb = (uint4*)bufB;
        for (int i = tid; i < NROW * RS / 8; i += 256) pb[i] = z;
    }

    // ---- conv1: 1->5ch k=3 relu, straight from global x, full-row writes ----
    {
        const float* xrow = x + (size_t)bid * TT;
        const int t0 = tid * 2;
        float xm  = (t0 > 0) ? xrow[t0 - 1] : 0.f;
        float x0v = xrow[t0];
        float x1v = xrow[t0 + 1];
        float xp  = (t0 < TT - 2) ? xrow[t0 + 2] : 0.f;
        h8 r0 = {}, r1 = {};
        #pragma unroll
        for (int o = 0; o < 5; ++o) {
            float k0 = w1[o * 3], k1 = w1[o * 3 + 1], k2 = w1[o * 3 + 2], bb = b1[o];
            float a0 = fmaf(k0, xm,  fmaf(k1, x0v, fmaf(k2, x1v, bb)));
            float a1 = fmaf(k0, x0v, fmaf(k1, x1v, fmaf(k2, xp,  bb)));
            r0[o] = (_Float16)fmaxf(a0, 0.f);
            r1[o] = (_Float16)fmaxf(a1, 0.f);
        }
        h8 zz = {};
        *(h8*)&bufA[(t0 + RH) * RS] = r0;
        *(h8*)&bufA[(t0 + RH) * RS + 8] = zz;
        *(h8*)&bufA[(t0 + 1 + RH) * RS] = r1;
        *(h8*)&bufA[(t0 + 1 + RH) * RS + 8] = zz;
    }
    __syncthreads();

    conv_stage<5, 2, 0>(bufA, bufB, wtab, 0, b2);       // conv2 (A->B)
    __syncthreads();
    conv_stage<7, 3, 1>(bufB, bufA, wtab, 320, b3);     // conv3 (tanh) (B->A)
    __syncthreads();
    vq_stage(bufA, bufB, wtab, c2tab);                  // VQ (A->B)
    __syncthreads();
    conv_stage<5, 2, 0>(bufB, bufA, wtab, 768, d1b);    // d1 (B->A)
    __syncthreads();
    conv_stage_flat<5, 2>(bufA, flat + (size_t)bid * (10 * TT),
                          wtab, 1088, d2b);             // d2 -> global
}

// ---------------------------------------------------------------------------
// FC: BM=128, BN=64, K split 8 ways (K=640/slice, 10 staging steps).
// grid 512 = 64 tiles x 8 kslices, 2 blocks/CU (pipeline overlap).
// bid: [2:0]=n-tile (== XCD id -> one 640KB W panel L2-resident per XCD),
// [5:3]=kslice (same XCD as its tile -> A panel fetched once per XCD),
// [8:6]=m-tile. Last-finishing block per tile reduces the 8 slices + bias +
// tanh -> out (fc_reduce launch eliminated; reduction overlaps other tiles).
__global__ __launch_bounds__(256, 2) void fc_partial_kernel(
    const _Float16* __restrict__ A,    // flat (1024, 5120)
    const _Float16* __restrict__ W,    // fcw_h (512, 5120)
    const float* __restrict__ bias,    // (512)
    float* __restrict__ partial,       // (64 tiles, 8 ks, 128, 64) f32
    unsigned* __restrict__ tilecnt,    // (64), zeroed by prep each call
    float* __restrict__ out)           // (1024, 512)
{
    __shared__ __align__(16) unsigned char smem[49152];  // 2 x (16K A + 8K W)

    const int tid = threadIdx.x;
    const int lane = tid & 63;
    const int w = tid >> 6;
    const int l31 = lane & 31;
    const int hi = lane >> 5;

    const int bid = blockIdx.x;
    const int nt  = bid & 7;
    const int ks8 = (bid >> 3) & 7;
    const int mt  = bid >> 6;
    const int tile = mt * 8 + nt;
    const int m0 = mt * 128;
    const int n0 = nt * 64;
    const int kbase = ks8 * 640;

    const _Float16* Asrc = A + (size_t)m0 * K_FC + kbase;
    const _Float16* Wsrc = W + (size_t)n0 * K_FC + kbase;

    f32x16 acc0 = {}, acc1 = {};

    auto stage = [&](int buf, int s) {
        unsigned char* Ad = smem + buf * 24576;
        unsigned char* Bd = Ad + 16384;
        const int k0 = s * 64;
        #pragma unroll
        for (int p = 0; p < 4; ++p) {                  // A: 128 rows x 8 chunks
            const int idx = p * 256 + tid;
            const int row = idx >> 3;
            const int c = idx & 7;
            const int csrc = c ^ (row & 7);
            __builtin_amdgcn_global_load_lds(
                (GAS*)(Asrc + (size_t)row * K_FC + k0 + csrc * 8),
                (LAS*)(Ad + idx * 16), 16, 0, 0);
        }
        #pragma unroll
        for (int p = 0; p < 2; ++p) {                  // W: 64 rows x 8 chunks
            const int idx = p * 256 + tid;
            const int row = idx >> 3;
            const int c = idx & 7;
            const int csrc = c ^ (row & 7);
            __builtin_amdgcn_global_load_lds(
                (GAS*)(Wsrc + (size_t)row * K_FC + k0 + csrc * 8),
                (LAS*)(Bd + idx * 16), 16, 0, 0);
        }
    };

    stage(0, 0);
    __syncthreads();

    for (int s = 0; s < 10; ++s) {
        const int cur = s & 1;
        if (s + 1 < 10) stage(cur ^ 1, s + 1);

        const unsigned char* Ab = smem + cur * 24576;
        const unsigned char* Bb = Ab + 16384;
        const int ar = w * 32 + l31;                   // this lane's A row
        #pragma unroll
        for (int ks = 0; ks < 4; ++ks) {
            const int kc = ks * 2 + hi;
            h8 af  = *(const h8*)(Ab + ar * 128 + ((kc ^ (ar & 7)) << 4));
            h8 bf0 = *(const h8*)(Bb + l31 * 128 + ((kc ^ (l31 & 7)) << 4));
            h8 bf1 = *(const h8*)(Bb + (l31 + 32) * 128 + ((kc ^ ((l31 + 32) & 7)) << 4));
            acc0 = __builtin_amdgcn_mfma_f32_32x32x16_f16(af, bf0, acc0, 0, 0, 0);
            acc1 = __builtin_amdgcn_mfma_f32_32x32x16_f16(af, bf1, acc1, 0, 0, 0);
        }
        __syncthreads();
    }

    // ---- write this slice's partial tile: [tile][ks8][mloc][nloc] f32 ----
    float* base = partial + ((size_t)tile * 8 + ks8) * (128 * 64);
    #pragma unroll
    for (int r = 0; r < 16; ++r) {
        const int mloc = w * 32 + (r & 3) + 8 * (r >> 2) + 4 * hi;
        base[mloc * 64 + l31]      = acc0[r];
        base[mloc * 64 + 32 + l31] = acc1[r];
    }

    // ---- last-block-done: 8th finisher reduces the tile ----
    __threadfence();
    __shared__ unsigned donecnt;
    if (tid == 0) donecnt = atomicAdd(&tilecnt[tile], 1u);
    __syncthreads();
    if (donecnt != 7u) return;
    __threadfence();

    const float* tb = partial + (size_t)tile * (8 * 128 * 64);
    for (int i = tid * 4; i < 128 * 64; i += 1024) {       // float4 per thread
        float4 s = *(const float4*)&tb[i];
        #pragma unroll
        for (int ksr = 1; ksr < 8; ++ksr) {
            float4 p = *(const float4*)&tb[ksr * 8192 + i];
            s.x += p.x; s.y += p.y; s.z += p.z; s.w += p.w;
        }
        const int mloc = i >> 6;
        const int nloc = i & 63;
        float4 bv = *(const float4*)&bias[n0 + nloc];
        float4 o;
        o.x = fast_tanh(s.x + bv.x);
        o.y = fast_tanh(s.y + bv.y);
        o.z = fast_tanh(s.z + bv.z);
        o.w = fast_tanh(s.w + bv.w);
        *(float4*)&out[(size_t)(m0 + mloc) * 512 + n0 + nloc] = o;
    }
}

extern "C" void kernel_launch(void* const* d_in, const int* in_sizes, int n_in,
                              void* d_out, int out_size, void* d_ws, size_t ws_size,
                              hipStream_t stream) {
    const float* x    = (const float*)d_in[0];
    const float* w1   = (const float*)d_in[1];
    const float* b1   = (const float*)d_in[2];
    const float* w2   = (const float*)d_in[3];
    const float* b2   = (const float*)d_in[4];
    const float* w3   = (const float*)d_in[5];
    const float* b3   = (const float*)d_in[6];
    const float* code = (const float*)d_in[7];
    const float* d1w  = (const float*)d_in[8];
    const float* d1b  = (const float*)d_in[9];
    const float* d2w  = (const float*)d_in[10];
    const float* d2b  = (const float*)d_in[11];
    const float* fcw  = (const float*)d_in[12];
    const float* fcb  = (const float*)d_in[13];
    float* out = (float*)d_out;

    _Float16* flat_h  = (_Float16*)d_ws;                             // 10 MB @0
    _Float16* fcw_h   = (_Float16*)((char*)d_ws + 10485760);         //  5 MB
    float*    partial = (float*)((char*)d_ws + 16777216);            // 16 MB
    uint4*    wtab    = (uint4*)((char*)d_ws + 33554432);            // 25.6 KB
    unsigned* c2tab   = (unsigned*)((char*)d_ws + 33554432 + 25600); // 128 B
    unsigned* tilecnt = (unsigned*)((char*)d_ws + 33554432 + 25728); // 256 B

    const int Bsz = in_sizes[0] / TT;   // 1024

    prep_wtab_kernel<<<7, 256, 0, stream>>>(w2, w3, d1w, d2w, code, wtab,
                                            c2tab, tilecnt);
    enc_dec_kernel<<<Bsz + 1280, 256, 0, stream>>>(x, w1, b1, b2, b3, d1b, d2b,
                                                   wtab, c2tab, flat_h,
                                                   fcw, fcw_h, Bsz);
    fc_partial_kernel<<<512, 256, 0, stream>>>(flat_h, fcw_h, fcb,
                                               partial, tilecnt, out);
}

// Round 15
// 48.656 us; speedup vs baseline: 2.3407x; 2.3407x over previous
//
#include <hip/hip_runtime.h>
#include <hip/hip_bf16.h>

#define TT 512
#define RS 16       // activation row: 16 f16 ch-slots (32 B)
#define RH 8        // row halo (t=-8..519 -> rows 0..527)
#define NROW 528
#define K_FC 5120

typedef _Float16 h8 __attribute__((ext_vector_type(8)));
typedef float f32x16 __attribute__((ext_vector_type(16)));
typedef __attribute__((address_space(1))) const void GAS;
typedef __attribute__((address_space(3))) void LAS;

__device__ __forceinline__ float fast_tanh(float v) {
    float e = __expf(2.0f * v);
    return 1.0f - 2.0f / (e + 1.0f);
}
__device__ __forceinline__ unsigned pk(float a, float b) {
    return __builtin_bit_cast(unsigned, __builtin_amdgcn_cvt_pkrtz(a, b));
}

// ---------------------------------------------------------------------------
// wtab in MFMA A-fragment layout (32x32x16 f16): lane l -> row=l&31, k=(l>>5)*8+e
//  conv2 @0 (5j) | conv3 @320 (7j) | d1 @768 (5j) | d2 @1088 (5j)
//  cross @1408 (A[kc][ch]=2*code[ch][kc]) | q @1472 (2 ks)
//  c2tab: 32 f32 bits of (4 - sum_c code[c][k]^2)
__global__ __launch_bounds__(256) void prep_wtab_kernel(
    const float* __restrict__ w2, const float* __restrict__ w3,
    const float* __restrict__ d1w, const float* __restrict__ d2w,
    const float* __restrict__ code, uint4* __restrict__ wtab,
    unsigned* __restrict__ c2tab)
{
    const int i = blockIdx.x * 256 + threadIdx.x;
    if (i < 1600) {
        const int lane = i & 63;
        const int o = lane & 31;
        const int hi = lane >> 5;
        h8 v = {};
        if (i < 320) {
            const int j = i >> 6;
            #pragma unroll
            for (int e = 0; e < 8; ++e) {
                int k = hi * 8 + e;
                if (o < 10 && k < 5) v[e] = (_Float16)w2[(o * 5 + k) * 5 + j];
            }
        } else if (i < 768) {
            const int j = (i - 320) >> 6;
            #pragma unroll
            for (int e = 0; e < 8; ++e) {
                int k = hi * 8 + e;
                if (o < 10 && k < 10) v[e] = (_Float16)w3[(o * 10 + k) * 7 + j];
            }
        } else if (i < 1088) {
            const int j = (i - 768) >> 6;
            #pragma unroll
            for (int e = 0; e < 8; ++e) {
                int k = hi * 8 + e;
                if (o < 10 && k < 10) v[e] = (_Float16)d1w[(o * 10 + k) * 5 + j];
            }
        } else if (i < 1408) {
            const int j = (i - 1088) >> 6;
            #pragma unroll
            for (int e = 0; e < 8; ++e) {
                int k = hi * 8 + e;
                if (o < 10 && k < 10) v[e] = (_Float16)d2w[(o * 10 + k) * 5 + j];
            }
        } else if (i < 1472) {
            #pragma unroll
            for (int e = 0; e < 8; ++e) {
                int ch = hi * 8 + e;
                if (ch < 10) v[e] = (_Float16)(2.0f * code[ch * 32 + o]);
            }
        } else {
            const int ks = (i - 1472) >> 6;
            #pragma unroll
            for (int e = 0; e < 8; ++e) {
                int kc = ks * 16 + hi * 8 + e;
                if (o < 10) v[e] = (_Float16)code[o * 32 + kc];
            }
        }
        wtab[i] = __builtin_bit_cast(uint4, v);
    } else if (i < 1632) {
        int k = i - 1600;
        float s = 0.f;
        for (int c = 0; c < 10; ++c) { float cv = code[c * 32 + k]; s = fmaf(cv, cv, s); }
        c2tab[k] = __float_as_uint(4.0f - s);
    }
}

// ---------------------------------------------------------------------------
// Conv stage via J MFMAs per 32-t tile; C-layout row m=(r&3)+8*(r>>2)+4*hi.
template<int J, int P, int ACT>   // ACT: 0 relu, 1 tanh
__device__ __forceinline__ void conv_stage(
    const _Float16* __restrict__ src, _Float16* __restrict__ dst,
    const uint4* __restrict__ wtab, int wbase, const float* __restrict__ bsrc)
{
    const int tid = threadIdx.x;
    const int lane = tid & 63;
    const int wv = tid >> 6;
    const int l31 = lane & 31;
    const int hi = lane >> 5;

    uint4 wf[J];
    #pragma unroll
    for (int j = 0; j < J; ++j) wf[j] = wtab[wbase + j * 64 + lane];
    float bias[6];
    #pragma unroll
    for (int r = 0; r < 6; ++r) {
        int m = (r & 3) + 8 * (r >> 2) + 4 * hi;
        bias[r] = (m < 10) ? bsrc[m] : 0.f;
    }

    #pragma unroll 2
    for (int tile = 0; tile < 4; ++tile) {
        const int tcol = wv * 128 + tile * 32 + l31;
        f32x16 acc = {};
        #pragma unroll
        for (int j = 0; j < J; ++j) {
            h8 bf = *(const h8*)(src + (tcol + RH - P + j) * RS + hi * 8);
            acc = __builtin_amdgcn_mfma_f32_32x32x16_f16(
                __builtin_bit_cast(h8, wf[j]), bf, acc, 0, 0, 0);
        }
        float v[6];
        #pragma unroll
        for (int r = 0; r < 6; ++r) {
            float t = acc[r] + bias[r];
            v[r] = (ACT == 0) ? fmaxf(t, 0.f) : fast_tanh(t);
        }
        unsigned* drow = (unsigned*)(dst + (tcol + RH) * RS);
        uint2 s1v; s1v.x = pk(v[0], v[1]); s1v.y = pk(v[2], v[3]);
        *(uint2*)(drow + hi * 2) = s1v;
        if (!hi) drow[4] = pk(v[4], v[5]);
    }
}

// Final stage: relu, store straight to flat[c*512 + t] in global.
template<int J, int P>
__device__ __forceinline__ void conv_stage_flat(
    const _Float16* __restrict__ src, _Float16* __restrict__ flatrow,
    const uint4* __restrict__ wtab, int wbase, const float* __restrict__ bsrc)
{
    const int tid = threadIdx.x;
    const int lane = tid & 63;
    const int wv = tid >> 6;
    const int l31 = lane & 31;
    const int hi = lane >> 5;

    uint4 wf[J];
    #pragma unroll
    for (int j = 0; j < J; ++j) wf[j] = wtab[wbase + j * 64 + lane];
    float bias[6];
    #pragma unroll
    for (int r = 0; r < 6; ++r) {
        int m = (r & 3) + 8 * (r >> 2) + 4 * hi;
        bias[r] = (m < 10) ? bsrc[m] : 0.f;
    }

    #pragma unroll 2
    for (int tile = 0; tile < 4; ++tile) {
        const int tcol = wv * 128 + tile * 32 + l31;
        f32x16 acc = {};
        #pragma unroll
        for (int j = 0; j < J; ++j) {
            h8 bf = *(const h8*)(src + (tcol + RH - P + j) * RS + hi * 8);
            acc = __builtin_amdgcn_mfma_f32_32x32x16_f16(
                __builtin_bit_cast(h8, wf[j]), bf, acc, 0, 0, 0);
        }
        #pragma unroll
        for (int r = 0; r < 4; ++r)
            flatrow[(r + 4 * hi) * TT + tcol] = (_Float16)fmaxf(acc[r] + bias[r], 0.f);
        if (!hi) {
            flatrow[8 * TT + tcol] = (_Float16)fmaxf(acc[4] + bias[4], 0.f);
            flatrow[9 * TT + tcol] = (_Float16)fmaxf(acc[5] + bias[5], 0.f);
        }
    }
}

// VQ: 1 MFMA scores, exp, denom shfl, packed-f16 half-wave exchange, 2 MFMA q.
__device__ __forceinline__ void vq_stage(
    const _Float16* __restrict__ src, _Float16* __restrict__ dst,
    const uint4* __restrict__ wtab, const unsigned* __restrict__ c2tab)
{
    const int tid = threadIdx.x;
    const int lane = tid & 63;
    const int wv = tid >> 6;
    const int l31 = lane & 31;
    const int hi = lane >> 5;

    const h8 wcr = __builtin_bit_cast(h8, wtab[1408 + lane]);
    const h8 wq0 = __builtin_bit_cast(h8, wtab[1472 + lane]);
    const h8 wq1 = __builtin_bit_cast(h8, wtab[1536 + lane]);
    float c2s[16];
    #pragma unroll
    for (int r = 0; r < 16; ++r)
        c2s[r] = __uint_as_float(c2tab[(r & 3) + 8 * (r >> 2) + 4 * hi]);

    #pragma unroll 2
    for (int tile = 0; tile < 4; ++tile) {
        const int tcol = wv * 128 + tile * 32 + l31;
        h8 bf = *(const h8*)(src + (tcol + RH) * RS + hi * 8);
        f32x16 sacc = {};
        sacc = __builtin_amdgcn_mfma_f32_32x32x16_f16(wcr, bf, sacc, 0, 0, 0);

        float e[16], sum = 0.f;
        #pragma unroll
        for (int r = 0; r < 16; ++r) { e[r] = __expf(sacc[r] + c2s[r]); sum += e[r]; }
        float inv = 1.0f / (sum + __shfl_xor(sum, 32));

        unsigned epk[8], sopk[8];
        #pragma unroll
        for (int q = 0; q < 8; ++q) epk[q] = pk(e[2 * q], e[2 * q + 1]);
        #pragma unroll
        for (int q = 0; q < 8; ++q) sopk[q] = (unsigned)__shfl_xor((int)epk[q], 32);

        uint4 b0u, b1u;
        b0u.x = hi ? sopk[2] : epk[0]; b0u.y = hi ? sopk[3] : epk[1];
        b0u.z = hi ? epk[2] : sopk[0]; b0u.w = hi ? epk[3] : sopk[1];
        b1u.x = hi ? sopk[6] : epk[4]; b1u.y = hi ? sopk[7] : epk[5];
        b1u.z = hi ? epk[6] : sopk[4]; b1u.w = hi ? epk[7] : sopk[5];

        f32x16 qacc = {};
        qacc = __builtin_amdgcn_mfma_f32_32x32x16_f16(wq0, __builtin_bit_cast(h8, b0u), qacc, 0, 0, 0);
        qacc = __builtin_amdgcn_mfma_f32_32x32x16_f16(wq1, __builtin_bit_cast(h8, b1u), qacc, 0, 0, 0);

        float v[6];
        #pragma unroll
        for (int r = 0; r < 6; ++r) v[r] = qacc[r] * inv;
        unsigned* drow = (unsigned*)(dst + (tcol + RH) * RS);
        uint2 s1v; s1v.x = pk(v[0], v[1]); s1v.y = pk(v[2], v[3]);
        *(uint2*)(drow + hi * 2) = s1v;
        if (!hi) drow[4] = pk(v[4], v[5]);
    }
}

// ---------------------------------------------------------------------------
// Block-cooperative enc/dec (R11/R13 structure). Blocks >= nenc convert fcw
// f32->f16 (consumed only by the later fc launch).
__global__ __launch_bounds__(256, 4) void enc_dec_kernel(
    const float* __restrict__ x,
    const float* __restrict__ w1, const float* __restrict__ b1,
    const float* __restrict__ b2, const float* __restrict__ b3,
    const float* __restrict__ d1b, const float* __restrict__ d2b,
    const uint4* __restrict__ wtab, const unsigned* __restrict__ c2tab,
    _Float16* __restrict__ flat,
    const float* __restrict__ fcw, _Float16* __restrict__ fcw_h, int nenc)
{
    __shared__ __align__(16) _Float16 bufA[NROW * RS];
    __shared__ __align__(16) _Float16 bufB[NROW * RS];

    const int tid = threadIdx.x;
    const int bid = blockIdx.x;

    if (bid >= nenc) {   // fcw f32 -> f16 conversion
        int i = (bid - nenc) * 256 + tid;
        float4 a = ((const float4*)fcw)[i * 2];
        float4 b4 = ((const float4*)fcw)[i * 2 + 1];
        h8 v;
        v[0] = (_Float16)a.x;  v[1] = (_Float16)a.y;
        v[2] = (_Float16)a.z;  v[3] = (_Float16)a.w;
        v[4] = (_Float16)b4.x; v[5] = (_Float16)b4.y;
        v[6] = (_Float16)b4.z; v[7] = (_Float16)b4.w;
        *(h8*)&fcw_h[(size_t)i * 8] = v;
        return;
    }

    // ---- init: zero bufA halo rows (conv1 writes the rest) + all of bufB ----
    if (tid < 32) {
        int r = tid >> 1, half = tid & 1;
        int rowz = (r < 8) ? r : 512 + r;       // rows 0..7, 520..527
        uint4 z = {0, 0, 0, 0};
        *(uint4*)(bufA + rowz * RS + half * 8) = z;
    }
    {
        uint4 z = {0, 0, 0, 0};
        uint4* pb = (uint4*)bufB;
        for (int i = tid; i < NROW * RS / 8; i += 256) pb[i] = z;
    }

    // ---- conv1: 1->5ch k=3 relu, straight from global x, full-row writes ----
    {
        const float* xrow = x + (size_t)bid * TT;
        const int t0 = tid * 2;
        float xm  = (t0 > 0) ? xrow[t0 - 1] : 0.f;
        float x0v = xrow[t0];
        float x1v = xrow[t0 + 1];
        float xp  = (t0 < TT - 2) ? xrow[t0 + 2] : 0.f;
        h8 r0 = {}, r1 = {};
        #pragma unroll
        for (int o = 0; o < 5; ++o) {
            float k0 = w1[o * 3], k1 = w1[o * 3 + 1], k2 = w1[o * 3 + 2], bb = b1[o];
            float a0 = fmaf(k0, xm,  fmaf(k1, x0v, fmaf(k2, x1v, bb)));
            float a1 = fmaf(k0, x0v, fmaf(k1, x1v, fmaf(k2, xp,  bb)));
            r0[o] = (_Float16)fmaxf(a0, 0.f);
            r1[o] = (_Float16)fmaxf(a1, 0.f);
        }
        h8 zz = {};
        *(h8*)&bufA[(t0 + RH) * RS] = r0;
        *(h8*)&bufA[(t0 + RH) * RS + 8] = zz;
        *(h8*)&bufA[(t0 + 1 + RH) * RS] = r1;
        *(h8*)&bufA[(t0 + 1 + RH) * RS + 8] = zz;
    }
    __syncthreads();

    conv_stage<5, 2, 0>(bufA, bufB, wtab, 0, b2);       // conv2 (A->B)
    __syncthreads();
    conv_stage<7, 3, 1>(bufB, bufA, wtab, 320, b3);     // conv3 (tanh) (B->A)
    __syncthreads();
    vq_stage(bufA, bufB, wtab, c2tab);                  // VQ (A->B)
    __syncthreads();
    conv_stage<5, 2, 0>(bufB, bufA, wtab, 768, d1b);    // d1 (B->A)
    __syncthreads();
    conv_stage_flat<5, 2>(bufA, flat + (size_t)bid * (10 * TT),
                          wtab, 1088, d2b);             // d2 -> global
}

// ---------------------------------------------------------------------------
// FC partials: BM=128, BN=64, K split 8 ways (K=640/slice, 10 staging steps).
// grid 512 = 64 tiles x 8 kslices, 2 blocks/CU so one block's MFMA hides the
// other's barrier/vmcnt drains. NO device-scope fences (R14 lesson: a
// __threadfence in the hot path flushes per-XCD L2 and cost 12x).
// bid: [2:0]=n-tile (XCD-pinned W panel), [5:3]=kslice, [8:6]=m-tile.
__global__ __launch_bounds__(256, 2) void fc_partial_kernel(
    const _Float16* __restrict__ A,    // flat (1024, 5120)
    const _Float16* __restrict__ W,    // fcw_h (512, 5120)
    float* __restrict__ partial)       // (8, 1024, 512) f32
{
    __shared__ __align__(16) unsigned char smem[49152];  // 2 x (16K A + 8K W)

    const int tid = threadIdx.x;
    const int lane = tid & 63;
    const int w = tid >> 6;
    const int l31 = lane & 31;
    const int hi = lane >> 5;

    const int bid = blockIdx.x;
    const int nt  = bid & 7;
    const int ks8 = (bid >> 3) & 7;
    const int mt  = bid >> 6;
    const int m0 = mt * 128;
    const int n0 = nt * 64;
    const int kbase = ks8 * 640;

    const _Float16* Asrc = A + (size_t)m0 * K_FC + kbase;
    const _Float16* Wsrc = W + (size_t)n0 * K_FC + kbase;

    f32x16 acc0 = {}, acc1 = {};

    auto stage = [&](int buf, int s) {
        unsigned char* Ad = smem + buf * 24576;
        unsigned char* Bd = Ad + 16384;
        const int k0 = s * 64;
        #pragma unroll
        for (int p = 0; p < 4; ++p) {                  // A: 128 rows x 8 chunks
            const int idx = p * 256 + tid;
            const int row = idx >> 3;
            const int c = idx & 7;
            const int csrc = c ^ (row & 7);
            __builtin_amdgcn_global_load_lds(
                (GAS*)(Asrc + (size_t)row * K_FC + k0 + csrc * 8),
                (LAS*)(Ad + idx * 16), 16, 0, 0);
        }
        #pragma unroll
        for (int p = 0; p < 2; ++p) {                  // W: 64 rows x 8 chunks
            const int idx = p * 256 + tid;
            const int row = idx >> 3;
            const int c = idx & 7;
            const int csrc = c ^ (row & 7);
            __builtin_amdgcn_global_load_lds(
                (GAS*)(Wsrc + (size_t)row * K_FC + k0 + csrc * 8),
                (LAS*)(Bd + idx * 16), 16, 0, 0);
        }
    };

    stage(0, 0);
    __syncthreads();

    for (int s = 0; s < 10; ++s) {
        const int cur = s & 1;
        if (s + 1 < 10) stage(cur ^ 1, s + 1);

        const unsigned char* Ab = smem + cur * 24576;
        const unsigned char* Bb = Ab + 16384;
        const int ar = w * 32 + l31;                   // this lane's A row
        #pragma unroll
        for (int ks = 0; ks < 4; ++ks) {
            const int kc = ks * 2 + hi;
            h8 af  = *(const h8*)(Ab + ar * 128 + ((kc ^ (ar & 7)) << 4));
            h8 bf0 = *(const h8*)(Bb + l31 * 128 + ((kc ^ (l31 & 7)) << 4));
            h8 bf1 = *(const h8*)(Bb + (l31 + 32) * 128 + ((kc ^ ((l31 + 32) & 7)) << 4));
            acc0 = __builtin_amdgcn_mfma_f32_32x32x16_f16(af, bf0, acc0, 0, 0, 0);
            acc1 = __builtin_amdgcn_mfma_f32_32x32x16_f16(af, bf1, acc1, 0, 0, 0);
        }
        __syncthreads();
    }

    // write f32 partial: slice-major full matrix, coalesced
    float* base = partial + (size_t)ks8 * (1024 * 512);
    #pragma unroll
    for (int r = 0; r < 16; ++r) {
        const int m = m0 + w * 32 + (r & 3) + 8 * (r >> 2) + 4 * hi;
        base[(size_t)m * 512 + n0 + l31]      = acc0[r];
        base[(size_t)m * 512 + n0 + 32 + l31] = acc1[r];
    }
}

// ---------------------------------------------------------------------------
// Reduce 8 K-slices + bias + tanh -> out. grid 1024 x 256, 2 els/thread.
__global__ __launch_bounds__(256) void fc_reduce_kernel(
    const float* __restrict__ partial, const float* __restrict__ bias,
    float* __restrict__ out)
{
    const int i = (blockIdx.x * 256 + threadIdx.x) * 2;
    float2 s = *(const float2*)&partial[i];
    #pragma unroll
    for (int k = 1; k < 8; ++k) {
        float2 p = *(const float2*)&partial[(size_t)k * 524288 + i];
        s.x += p.x; s.y += p.y;
    }
    const int n = i & 511;
    float2 o;
    o.x = fast_tanh(s.x + bias[n]);
    o.y = fast_tanh(s.y + bias[n + 1]);
    *(float2*)&out[i] = o;
}

extern "C" void kernel_launch(void* const* d_in, const int* in_sizes, int n_in,
                              void* d_out, int out_size, void* d_ws, size_t ws_size,
                              hipStream_t stream) {
    const float* x    = (const float*)d_in[0];
    const float* w1   = (const float*)d_in[1];
    const float* b1   = (const float*)d_in[2];
    const float* w2   = (const float*)d_in[3];
    const float* b2   = (const float*)d_in[4];
    const float* w3   = (const float*)d_in[5];
    const float* b3   = (const float*)d_in[6];
    const float* code = (const float*)d_in[7];
    const float* d1w  = (const float*)d_in[8];
    const float* d1b  = (const float*)d_in[9];
    const float* d2w  = (const float*)d_in[10];
    const float* d2b  = (const float*)d_in[11];
    const float* fcw  = (const float*)d_in[12];
    const float* fcb  = (const float*)d_in[13];
    float* out = (float*)d_out;

    _Float16* flat_h  = (_Float16*)d_ws;                             // 10 MB @0
    _Float16* fcw_h   = (_Float16*)((char*)d_ws + 10485760);         //  5 MB
    float*    partial = (float*)((char*)d_ws + 16777216);            // 16 MB
    uint4*    wtab    = (uint4*)((char*)d_ws + 33554432);            // 25.6 KB
    unsigned* c2tab   = (unsigned*)((char*)d_ws + 33554432 + 25600); // 128 B

    const int Bsz = in_sizes[0] / TT;   // 1024

    prep_wtab_kernel<<<7, 256, 0, stream>>>(w2, w3, d1w, d2w, code, wtab, c2tab);
    enc_dec_kernel<<<Bsz + 1280, 256, 0, stream>>>(x, w1, b1, b2, b3, d1b, d2b,
                                                   wtab, c2tab, flat_h,
                                                   fcw, fcw_h, Bsz);
    fc_partial_kernel<<<512, 256, 0, stream>>>(flat_h, fcw_h, partial);
    fc_reduce_kernel<<<1024, 256, 0, stream>>>(partial, fcb, out);
}

// Round 16
// 47.382 us; speedup vs baseline: 2.4036x; 1.0269x over previous
//
#include <hip/hip_runtime.h>
#include <hip/hip_bf16.h>

#define TT 512
#define RS 16       // activation row: 16 f16 ch-slots (32 B)
#define RH 8        // row halo (t=-8..519 -> rows 0..527)
#define NROW 528
#define K_FC 5120

typedef _Float16 h8 __attribute__((ext_vector_type(8)));
typedef float f32x16 __attribute__((ext_vector_type(16)));
typedef __attribute__((address_space(1))) const void GAS;
typedef __attribute__((address_space(3))) void LAS;

__device__ __forceinline__ float fast_tanh(float v) {
    float e = __expf(2.0f * v);
    return 1.0f - 2.0f / (e + 1.0f);
}
__device__ __forceinline__ unsigned pk(float a, float b) {
    return __builtin_bit_cast(unsigned, __builtin_amdgcn_cvt_pkrtz(a, b));
}

// ---------------------------------------------------------------------------
// wtab in MFMA A-fragment layout (32x32x16 f16): lane l -> row=l&31, k=(l>>5)*8+e
//  conv2 @0 (5j) | conv3 @320 (7j) | d1 @768 (5j) | d2 @1088 (5j)
//  cross @1408 (A[kc][ch]=2*code[ch][kc]) | q @1472 (2 ks)
//  c2tab: 32 f32 bits of (4 - sum_c code[c][k]^2)
__global__ __launch_bounds__(256) void prep_wtab_kernel(
    const float* __restrict__ w2, const float* __restrict__ w3,
    const float* __restrict__ d1w, const float* __restrict__ d2w,
    const float* __restrict__ code, uint4* __restrict__ wtab,
    unsigned* __restrict__ c2tab)
{
    const int i = blockIdx.x * 256 + threadIdx.x;
    if (i < 1600) {
        const int lane = i & 63;
        const int o = lane & 31;
        const int hi = lane >> 5;
        h8 v = {};
        if (i < 320) {
            const int j = i >> 6;
            #pragma unroll
            for (int e = 0; e < 8; ++e) {
                int k = hi * 8 + e;
                if (o < 10 && k < 5) v[e] = (_Float16)w2[(o * 5 + k) * 5 + j];
            }
        } else if (i < 768) {
            const int j = (i - 320) >> 6;
            #pragma unroll
            for (int e = 0; e < 8; ++e) {
                int k = hi * 8 + e;
                if (o < 10 && k < 10) v[e] = (_Float16)w3[(o * 10 + k) * 7 + j];
            }
        } else if (i < 1088) {
            const int j = (i - 768) >> 6;
            #pragma unroll
            for (int e = 0; e < 8; ++e) {
                int k = hi * 8 + e;
                if (o < 10 && k < 10) v[e] = (_Float16)d1w[(o * 10 + k) * 5 + j];
            }
        } else if (i < 1408) {
            const int j = (i - 1088) >> 6;
            #pragma unroll
            for (int e = 0; e < 8; ++e) {
                int k = hi * 8 + e;
                if (o < 10 && k < 10) v[e] = (_Float16)d2w[(o * 10 + k) * 5 + j];
            }
        } else if (i < 1472) {
            #pragma unroll
            for (int e = 0; e < 8; ++e) {
                int ch = hi * 8 + e;
                if (ch < 10) v[e] = (_Float16)(2.0f * code[ch * 32 + o]);
            }
        } else {
            const int ks = (i - 1472) >> 6;
            #pragma unroll
            for (int e = 0; e < 8; ++e) {
                int kc = ks * 16 + hi * 8 + e;
                if (o < 10) v[e] = (_Float16)code[o * 32 + kc];
            }
        }
        wtab[i] = __builtin_bit_cast(uint4, v);
    } else if (i < 1632) {
        int k = i - 1600;
        float s = 0.f;
        for (int c = 0; c < 10; ++c) { float cv = code[c * 32 + k]; s = fmaf(cv, cv, s); }
        c2tab[k] = __float_as_uint(4.0f - s);
    }
}

// ---------------------------------------------------------------------------
// Conv stage with PRE-LOADED weight fragments (wf in registers, issued one
// stage ahead so the global-load latency is off the stage-entry critical path).
template<int J, int P, int ACT>   // ACT: 0 relu, 1 tanh
__device__ __forceinline__ void conv_stage_w(
    const uint4 (&wf)[J],
    const _Float16* __restrict__ src, _Float16* __restrict__ dst,
    const float* __restrict__ bsrc)
{
    const int tid = threadIdx.x;
    const int lane = tid & 63;
    const int wv = tid >> 6;
    const int l31 = lane & 31;
    const int hi = lane >> 5;

    float bias[6];
    #pragma unroll
    for (int r = 0; r < 6; ++r) {
        int m = (r & 3) + 8 * (r >> 2) + 4 * hi;
        bias[r] = (m < 10) ? bsrc[m] : 0.f;   // consumed only at epilogue
    }

    #pragma unroll 2
    for (int tile = 0; tile < 4; ++tile) {
        const int tcol = wv * 128 + tile * 32 + l31;
        f32x16 acc = {};
        #pragma unroll
        for (int j = 0; j < J; ++j) {
            h8 bf = *(const h8*)(src + (tcol + RH - P + j) * RS + hi * 8);
            acc = __builtin_amdgcn_mfma_f32_32x32x16_f16(
                __builtin_bit_cast(h8, wf[j]), bf, acc, 0, 0, 0);
        }
        float v[6];
        #pragma unroll
        for (int r = 0; r < 6; ++r) {
            float t = acc[r] + bias[r];
            v[r] = (ACT == 0) ? fmaxf(t, 0.f) : fast_tanh(t);
        }
        unsigned* drow = (unsigned*)(dst + (tcol + RH) * RS);
        uint2 s1v; s1v.x = pk(v[0], v[1]); s1v.y = pk(v[2], v[3]);
        *(uint2*)(drow + hi * 2) = s1v;
        if (!hi) drow[4] = pk(v[4], v[5]);
    }
}

// Final stage: relu, store straight to flat[c*512 + t] in global.
template<int J, int P>
__device__ __forceinline__ void conv_stage_flat_w(
    const uint4 (&wf)[J],
    const _Float16* __restrict__ src, _Float16* __restrict__ flatrow,
    const float* __restrict__ bsrc)
{
    const int tid = threadIdx.x;
    const int lane = tid & 63;
    const int wv = tid >> 6;
    const int l31 = lane & 31;
    const int hi = lane >> 5;

    float bias[6];
    #pragma unroll
    for (int r = 0; r < 6; ++r) {
        int m = (r & 3) + 8 * (r >> 2) + 4 * hi;
        bias[r] = (m < 10) ? bsrc[m] : 0.f;
    }

    #pragma unroll 2
    for (int tile = 0; tile < 4; ++tile) {
        const int tcol = wv * 128 + tile * 32 + l31;
        f32x16 acc = {};
        #pragma unroll
        for (int j = 0; j < J; ++j) {
            h8 bf = *(const h8*)(src + (tcol + RH - P + j) * RS + hi * 8);
            acc = __builtin_amdgcn_mfma_f32_32x32x16_f16(
                __builtin_bit_cast(h8, wf[j]), bf, acc, 0, 0, 0);
        }
        #pragma unroll
        for (int r = 0; r < 4; ++r)
            flatrow[(r + 4 * hi) * TT + tcol] = (_Float16)fmaxf(acc[r] + bias[r], 0.f);
        if (!hi) {
            flatrow[8 * TT + tcol] = (_Float16)fmaxf(acc[4] + bias[4], 0.f);
            flatrow[9 * TT + tcol] = (_Float16)fmaxf(acc[5] + bias[5], 0.f);
        }
    }
}

// VQ with pre-loaded fragments: 1 MFMA scores, exp, denom shfl, packed
// half-wave exchange, 2 MFMA q.
__device__ __forceinline__ void vq_stage_w(
    const uint4 (&wfq)[3],
    const _Float16* __restrict__ src, _Float16* __restrict__ dst,
    const unsigned* __restrict__ c2tab)
{
    const int tid = threadIdx.x;
    const int lane = tid & 63;
    const int wv = tid >> 6;
    const int l31 = lane & 31;
    const int hi = lane >> 5;

    const h8 wcr = __builtin_bit_cast(h8, wfq[0]);
    const h8 wq0 = __builtin_bit_cast(h8, wfq[1]);
    const h8 wq1 = __builtin_bit_cast(h8, wfq[2]);
    float c2s[16];
    #pragma unroll
    for (int r = 0; r < 16; ++r)
        c2s[r] = __uint_as_float(c2tab[(r & 3) + 8 * (r >> 2) + 4 * hi]);

    #pragma unroll 2
    for (int tile = 0; tile < 4; ++tile) {
        const int tcol = wv * 128 + tile * 32 + l31;
        h8 bf = *(const h8*)(src + (tcol + RH) * RS + hi * 8);
        f32x16 sacc = {};
        sacc = __builtin_amdgcn_mfma_f32_32x32x16_f16(wcr, bf, sacc, 0, 0, 0);

        float e[16], sum = 0.f;
        #pragma unroll
        for (int r = 0; r < 16; ++r) { e[r] = __expf(sacc[r] + c2s[r]); sum += e[r]; }
        float inv = 1.0f / (sum + __shfl_xor(sum, 32));

        unsigned epk[8], sopk[8];
        #pragma unroll
        for (int q = 0; q < 8; ++q) epk[q] = pk(e[2 * q], e[2 * q + 1]);
        #pragma unroll
        for (int q = 0; q < 8; ++q) sopk[q] = (unsigned)__shfl_xor((int)epk[q], 32);

        uint4 b0u, b1u;
        b0u.x = hi ? sopk[2] : epk[0]; b0u.y = hi ? sopk[3] : epk[1];
        b0u.z = hi ? epk[2] : sopk[0]; b0u.w = hi ? epk[3] : sopk[1];
        b1u.x = hi ? sopk[6] : epk[4]; b1u.y = hi ? sopk[7] : epk[5];
        b1u.z = hi ? epk[6] : sopk[4]; b1u.w = hi ? epk[7] : sopk[5];

        f32x16 qacc = {};
        qacc = __builtin_amdgcn_mfma_f32_32x32x16_f16(wq0, __builtin_bit_cast(h8, b0u), qacc, 0, 0, 0);
        qacc = __builtin_amdgcn_mfma_f32_32x32x16_f16(wq1, __builtin_bit_cast(h8, b1u), qacc, 0, 0, 0);

        float v[6];
        #pragma unroll
        for (int r = 0; r < 6; ++r) v[r] = qacc[r] * inv;
        unsigned* drow = (unsigned*)(dst + (tcol + RH) * RS);
        uint2 s1v; s1v.x = pk(v[0], v[1]); s1v.y = pk(v[2], v[3]);
        *(uint2*)(drow + hi * 2) = s1v;
        if (!hi) drow[4] = pk(v[4], v[5]);
    }
}

// ---------------------------------------------------------------------------
// Block-cooperative enc/dec with one-stage-ahead weight prefetch.
// Blocks >= nenc convert fcw f32->f16 (consumed only by the later fc launch).
__global__ __launch_bounds__(256, 4) void enc_dec_kernel(
    const float* __restrict__ x,
    const float* __restrict__ w1, const float* __restrict__ b1,
    const float* __restrict__ b2, const float* __restrict__ b3,
    const float* __restrict__ d1b, const float* __restrict__ d2b,
    const uint4* __restrict__ wtab, const unsigned* __restrict__ c2tab,
    _Float16* __restrict__ flat,
    const float* __restrict__ fcw, _Float16* __restrict__ fcw_h, int nenc)
{
    __shared__ __align__(16) _Float16 bufA[NROW * RS];
    __shared__ __align__(16) _Float16 bufB[NROW * RS];

    const int tid = threadIdx.x;
    const int bid = blockIdx.x;

    if (bid >= nenc) {   // fcw f32 -> f16 conversion
        int i = (bid - nenc) * 256 + tid;
        float4 a = ((const float4*)fcw)[i * 2];
        float4 b4 = ((const float4*)fcw)[i * 2 + 1];
        h8 v;
        v[0] = (_Float16)a.x;  v[1] = (_Float16)a.y;
        v[2] = (_Float16)a.z;  v[3] = (_Float16)a.w;
        v[4] = (_Float16)b4.x; v[5] = (_Float16)b4.y;
        v[6] = (_Float16)b4.z; v[7] = (_Float16)b4.w;
        *(h8*)&fcw_h[(size_t)i * 8] = v;
        return;
    }

    const int lane = tid & 63;

    // ---- prefetch conv2 weights immediately (in flight during init+conv1) --
    uint4 wf2[5];
    #pragma unroll
    for (int j = 0; j < 5; ++j) wf2[j] = wtab[j * 64 + lane];

    // ---- init: zero bufA halo rows (conv1 writes the rest) + all of bufB ----
    if (tid < 32) {
        int r = tid >> 1, half = tid & 1;
        int rowz = (r < 8) ? r : 512 + r;       // rows 0..7, 520..527
        uint4 z = {0, 0, 0, 0};
        *(uint4*)(bufA + rowz * RS + half * 8) = z;
    }
    {
        uint4 z = {0, 0, 0, 0};
        uint4* pb = (uint4*)bufB;
        for (int i = tid; i < NROW * RS / 8; i += 256) pb[i] = z;
    }

    // ---- conv1: 1->5ch k=3 relu, straight from global x, full-row writes ----
    {
        const float* xrow = x + (size_t)bid * TT;
        const int t0 = tid * 2;
        float xm  = (t0 > 0) ? xrow[t0 - 1] : 0.f;
        float x0v = xrow[t0];
        float x1v = xrow[t0 + 1];
        float xp  = (t0 < TT - 2) ? xrow[t0 + 2] : 0.f;
        h8 r0 = {}, r1 = {};
        #pragma unroll
        for (int o = 0; o < 5; ++o) {
            float k0 = w1[o * 3], k1 = w1[o * 3 + 1], k2 = w1[o * 3 + 2], bb = b1[o];
            float a0 = fmaf(k0, xm,  fmaf(k1, x0v, fmaf(k2, x1v, bb)));
            float a1 = fmaf(k0, x0v, fmaf(k1, x1v, fmaf(k2, xp,  bb)));
            r0[o] = (_Float16)fmaxf(a0, 0.f);
            r1[o] = (_Float16)fmaxf(a1, 0.f);
        }
        h8 zz = {};
        *(h8*)&bufA[(t0 + RH) * RS] = r0;
        *(h8*)&bufA[(t0 + RH) * RS + 8] = zz;
        *(h8*)&bufA[(t0 + 1 + RH) * RS] = r1;
        *(h8*)&bufA[(t0 + 1 + RH) * RS + 8] = zz;
    }

    // prefetch conv3 weights (hidden under conv2)
    uint4 wf3[7];
    #pragma unroll
    for (int j = 0; j < 7; ++j) wf3[j] = wtab[320 + j * 64 + lane];
    __syncthreads();

    conv_stage_w<5, 2, 0>(wf2, bufA, bufB, b2);        // conv2 (A->B)

    uint4 wfq[3];                                       // VQ weights (under conv3)
    #pragma unroll
    for (int r = 0; r < 3; ++r) wfq[r] = wtab[1408 + r * 64 + lane];
    __syncthreads();

    conv_stage_w<7, 3, 1>(wf3, bufB, bufA, b3);        // conv3 (tanh) (B->A)

    uint4 wfd1[5];                                      // d1 weights (under VQ)
    #pragma unroll
    for (int j = 0; j < 5; ++j) wfd1[j] = wtab[768 + j * 64 + lane];
    __syncthreads();

    vq_stage_w(wfq, bufA, bufB, c2tab);                 // VQ (A->B)

    uint4 wfd2[5];                                      // d2 weights (under d1)
    #pragma unroll
    for (int j = 0; j < 5; ++j) wfd2[j] = wtab[1088 + j * 64 + lane];
    __syncthreads();

    conv_stage_w<5, 2, 0>(wfd1, bufB, bufA, d1b);      // d1 (B->A)
    __syncthreads();

    conv_stage_flat_w<5, 2>(wfd2, bufA, flat + (size_t)bid * (10 * TT), d2b);
}

// ---------------------------------------------------------------------------
// FC partials (exact R13 config — best measured): BM=128, BN=64, K split 4
// ways (K=1280, 20 staging steps), grid 256 = 64 tiles x 4 kslices.
// bid: [2:0]=n-tile(XCD), [4:3]=kslice, [7:5]=m-tile. No device-scope fences.
__global__ __launch_bounds__(256, 1) void fc_partial_kernel(
    const _Float16* __restrict__ A,    // flat (1024, 5120)
    const _Float16* __restrict__ W,    // fcw_h (512, 5120)
    float* __restrict__ partial)       // (4, 1024, 512) f32
{
    __shared__ __align__(16) unsigned char smem[49152];  // 2 x (16K A + 8K W)

    const int tid = threadIdx.x;
    const int lane = tid & 63;
    const int w = tid >> 6;
    const int l31 = lane & 31;
    const int hi = lane >> 5;

    const int bid = blockIdx.x;
    const int tile = (bid & 7) | ((bid >> 5) << 3);   // 64 tiles
    const int ks4  = (bid >> 3) & 3;                  // K slice
    const int m0 = (tile >> 3) * 128;
    const int n0 = (tile & 7) * 64;
    const int kbase = ks4 * 1280;

    const _Float16* Asrc = A + (size_t)m0 * K_FC + kbase;
    const _Float16* Wsrc = W + (size_t)n0 * K_FC + kbase;

    f32x16 acc0 = {}, acc1 = {};

    auto stage = [&](int buf, int s) {
        unsigned char* Ad = smem + buf * 24576;
        unsigned char* Bd = Ad + 16384;
        const int k0 = s * 64;
        #pragma unroll
        for (int p = 0; p < 4; ++p) {                  // A: 128 rows x 8 chunks
            const int idx = p * 256 + tid;
            const int row = idx >> 3;
            const int c = idx & 7;
            const int csrc = c ^ (row & 7);
            __builtin_amdgcn_global_load_lds(
                (GAS*)(Asrc + (size_t)row * K_FC + k0 + csrc * 8),
                (LAS*)(Ad + idx * 16), 16, 0, 0);
        }
        #pragma unroll
        for (int p = 0; p < 2; ++p) {                  // W: 64 rows x 8 chunks
            const int idx = p * 256 + tid;
            const int row = idx >> 3;
            const int c = idx & 7;
            const int csrc = c ^ (row & 7);
            __builtin_amdgcn_global_load_lds(
                (GAS*)(Wsrc + (size_t)row * K_FC + k0 + csrc * 8),
                (LAS*)(Bd + idx * 16), 16, 0, 0);
        }
    };

    stage(0, 0);
    __syncthreads();

    for (int s = 0; s < 20; ++s) {
        const int cur = s & 1;
        if (s + 1 < 20) stage(cur ^ 1, s + 1);

        const unsigned char* Ab = smem + cur * 24576;
        const unsigned char* Bb = Ab + 16384;
        const int ar = w * 32 + l31;                   // this lane's A row
        #pragma unroll
        for (int ks = 0; ks < 4; ++ks) {
            const int kc = ks * 2 + hi;
            h8 af  = *(const h8*)(Ab + ar * 128 + ((kc ^ (ar & 7)) << 4));
            h8 bf0 = *(const h8*)(Bb + l31 * 128 + ((kc ^ (l31 & 7)) << 4));
            h8 bf1 = *(const h8*)(Bb + (l31 + 32) * 128 + ((kc ^ ((l31 + 32) & 7)) << 4));
            acc0 = __builtin_amdgcn_mfma_f32_32x32x16_f16(af, bf0, acc0, 0, 0, 0);
            acc1 = __builtin_amdgcn_mfma_f32_32x32x16_f16(af, bf1, acc1, 0, 0, 0);
        }
        __syncthreads();
    }

    float* base = partial + (size_t)ks4 * (1024 * 512);
    #pragma unroll
    for (int r = 0; r < 16; ++r) {
        const int m = m0 + w * 32 + (r & 3) + 8 * (r >> 2) + 4 * hi;
        base[(size_t)m * 512 + n0 + l31]      = acc0[r];
        base[(size_t)m * 512 + n0 + 32 + l31] = acc1[r];
    }
}

// ---------------------------------------------------------------------------
// Reduce 4 K-slices + bias + tanh -> out. grid 1024 x 256, 2 els/thread.
__global__ __launch_bounds__(256) void fc_reduce_kernel(
    const float* __restrict__ partial, const float* __restrict__ bias,
    float* __restrict__ out)
{
    const int i = (blockIdx.x * 256 + threadIdx.x) * 2;
    float2 p0 = *(const float2*)&partial[i];
    float2 p1 = *(const float2*)&partial[524288 + i];
    float2 p2 = *(const float2*)&partial[1048576 + i];
    float2 p3 = *(const float2*)&partial[1572864 + i];
    const int n = i & 511;
    float s0 = p0.x + p1.x + p2.x + p3.x + bias[n];
    float s1 = p0.y + p1.y + p2.y + p3.y + bias[n + 1];
    float2 o;
    o.x = fast_tanh(s0);
    o.y = fast_tanh(s1);
    *(float2*)&out[i] = o;
}

extern "C" void kernel_launch(void* const* d_in, const int* in_sizes, int n_in,
                              void* d_out, int out_size, void* d_ws, size_t ws_size,
                              hipStream_t stream) {
    const float* x    = (const float*)d_in[0];
    const float* w1   = (const float*)d_in[1];
    const float* b1   = (const float*)d_in[2];
    const float* w2   = (const float*)d_in[3];
    const float* b2   = (const float*)d_in[4];
    const float* w3   = (const float*)d_in[5];
    const float* b3   = (const float*)d_in[6];
    const float* code = (const float*)d_in[7];
    const float* d1w  = (const float*)d_in[8];
    const float* d1b  = (const float*)d_in[9];
    const float* d2w  = (const float*)d_in[10];
    const float* d2b  = (const float*)d_in[11];
    const float* fcw  = (const float*)d_in[12];
    const float* fcb  = (const float*)d_in[13];
    float* out = (float*)d_out;

    _Float16* flat_h  = (_Float16*)d_ws;                             // 10 MB @0
    _Float16* fcw_h   = (_Float16*)((char*)d_ws + 10485760);         //  5 MB
    float*    partial = (float*)((char*)d_ws + 16777216);            //  8 MB
    uint4*    wtab    = (uint4*)((char*)d_ws + 25165824);            // 25.6 KB
    unsigned* c2tab   = (unsigned*)((char*)d_ws + 25165824 + 25600); // 128 B

    const int Bsz = in_sizes[0] / TT;   // 1024

    prep_wtab_kernel<<<7, 256, 0, stream>>>(w2, w3, d1w, d2w, code, wtab, c2tab);
    enc_dec_kernel<<<Bsz + 1280, 256, 0, stream>>>(x, w1, b1, b2, b3, d1b, d2b,
                                                   wtab, c2tab, flat_h,
                                                   fcw, fcw_h, Bsz);
    fc_partial_kernel<<<256, 256, 0, stream>>>(flat_h, fcw_h, partial);
    fc_reduce_kernel<<<1024, 256, 0, stream>>>(partial, fcb, out);
}